// Round 2
// baseline (630.734 us; speedup 1.0000x reference)
//
#include <hip/hip_runtime.h>
#include <math.h>

#define TT 512
#define BB 512
#define CC 32
#define CIN 33
#define HH 128
#define EPSF 1e-12f
#define CH 16              // timesteps per gx-chunk staged in LDS
#define NCH (TT / CH)
#define HSP 160            // hs stride (halves)
#define GXSTR 516          // floats per gx row: 2064 B, 16B-aligned, 4*516%32==16... commit-only conflicts (proven free)

typedef _Float16 half8 __attribute__((ext_vector_type(8)));
typedef _Float16 half2v __attribute__((ext_vector_type(2)));
typedef float f32x4 __attribute__((ext_vector_type(4)));

#define MFMA16H(a, b, c) __builtin_amdgcn_mfma_f32_16x16x32_f16(a, b, c, 0, 0, 0)
// In-loop barrier: LDS visibility only (no vmcnt drain; staging loads stay in flight).
#define BARRIER() asm volatile("s_waitcnt lgkmcnt(0)\n\ts_barrier" ::: "memory")

__device__ __forceinline__ float fsig(float x) {
    return __builtin_amdgcn_rcpf(1.f + __expf(-x));
}
__device__ __forceinline__ float ftanh(float x) {
    return 1.f - 2.f * __builtin_amdgcn_rcpf(1.f + __expf(2.f * x));
}
// full-wave (64) sum via DPP; result valid on lane 63 ONLY.
__device__ __forceinline__ float wave_sum_dpp(float x) {
    x += __int_as_float(__builtin_amdgcn_update_dpp(0, __float_as_int(x), 0x111, 0xf, 0xf, true));
    x += __int_as_float(__builtin_amdgcn_update_dpp(0, __float_as_int(x), 0x112, 0xf, 0xf, true));
    x += __int_as_float(__builtin_amdgcn_update_dpp(0, __float_as_int(x), 0x114, 0xf, 0xf, true));
    x += __int_as_float(__builtin_amdgcn_update_dpp(0, __float_as_int(x), 0x118, 0xf, 0xf, true));
    x += __int_as_float(__builtin_amdgcn_update_dpp(0, __float_as_int(x), 0x142, 0xa, 0xf, true));
    x += __int_as_float(__builtin_amdgcn_update_dpp(0, __float_as_int(x), 0x143, 0xc, 0xf, true));
    return x;
}
// sum within each 16-lane row; result valid on lanes 15/31/47/63.
__device__ __forceinline__ float row_sum_dpp(float x) {
    x += __int_as_float(__builtin_amdgcn_update_dpp(0, __float_as_int(x), 0x111, 0xf, 0xf, true));
    x += __int_as_float(__builtin_amdgcn_update_dpp(0, __float_as_int(x), 0x112, 0xf, 0xf, true));
    x += __int_as_float(__builtin_amdgcn_update_dpp(0, __float_as_int(x), 0x114, 0xf, 0xf, true));
    x += __int_as_float(__builtin_amdgcn_update_dpp(0, __float_as_int(x), 0x118, 0xf, 0xf, true));
    return x;
}
// spin-load ws[t]: ws is 0xAA-poisoned each launch (sentinel). Relaxed order is
// sufficient; AGENT scope gives cross-XCD visibility. Iteration cap -> worst
// case is a wrong value, never a hang.
__device__ __forceinline__ float load_s(const float* p) {
    float v = __hip_atomic_load(p, __ATOMIC_RELAXED, __HIP_MEMORY_SCOPE_AGENT);
    for (int it = 0; it < 100000000 && __float_as_uint(v) == 0xAAAAAAAAu; ++it)
        v = __hip_atomic_load(p, __ATOMIC_RELAXED, __HIP_MEMORY_SCOPE_AGENT);
    return v;
}

// ---------------------------------------------------------------------------
// R20: RB=1, 512 blocks of 512 threads, LDS 71.5 KB -> TWO co-resident blocks
// per CU. The two blocks are mutually async, so one block's compute fills the
// other's barrier/ds_read/activation stalls (R19 showed ~60% per-step stall
// with a single lockstep block). Single batch row broadcast into all 16 MFMA
// A-rows; gx gate-interleaved float4 (1 ds_read_b128/lane/step). waves_per_eu
// (4,4) forces VGPR<=128 so 2-block co-residency (required by the ws spin
// protocol) cannot silently fail.
// ---------------------------------------------------------------------------
__global__ __attribute__((amdgpu_flat_work_group_size(512, 512), amdgpu_waves_per_eu(4, 4)))
void critic_fused(
    const float* __restrict__ x,
    const float* __restrict__ w_ih, const float* __restrict__ u_ih,
    const float* __restrict__ w_hh, const float* __restrict__ u_hh,
    const float* __restrict__ b_ih, const float* __restrict__ b_hh,
    const float* __restrict__ attn_w, const float* __restrict__ attn_b,
    const float* __restrict__ fc_w, const float* __restrict__ u_fc,
    const float* __restrict__ fc_b,
    float* __restrict__ ws,
    float* __restrict__ out)
{
    const int tid = threadIdx.x;
    const int w   = tid >> 6;          // wave 0..7
    const int l   = tid & 63;          // lane
    const int m   = l & 15;            // A-row / B-col index
    const int q   = l >> 4;            // quad 0..3
    const int b0  = blockIdx.x;        // batch row; ALSO the std timestep this block owns
    const int jcol = 16 * w + m;       // this lane's h column

    // ---- LDS (71.5 KB total -> 2 blocks/CU) ----
    __shared__ float4 sSS[8][8];                            // std wave-partials
    __shared__ float4 sQQ[8][8];
    __shared__ float stdp[8];                               // per-c4 std partials
    __shared__ float red[512];                              // sigma scratch
    __shared__ float vv[128];
    __shared__ float sigS[3];                               // sig_ih, sig_hh, sig_fc
    __shared__ __align__(16) _Float16 hs[2][HSP];           // h planes (1 row)
    __shared__ __align__(16) float gxs[2][CH][GXSTR];       // gate-interleaved gates_x
    __shared__ float bcast[2];                              // beta per parity
    __shared__ float SfS;
    __shared__ float part[8];                               // FC partials

    // ===== Phase A loads issued FIRST (HBM latency hidden by phase B) =====
    const int c4 = tid & 7;       // c = c4*4 .. c4*4+3
    const int bs = tid >> 3;      // 64 groups of 8 batch rows
    float4 xa[8];
#pragma unroll
    for (int i = 0; i < 8; ++i)
        xa[i] = *reinterpret_cast<const float4*>(
            x + ((size_t)(bs * 8 + i) * TT + b0) * CC + c4 * 4);

    // ===== sigma_hh projection in the loads' shadow (L2-bound) =====
    {
        const int c = tid & 127, qq = tid >> 7;
        const float* wp = w_hh + (size_t)(qq * 128) * HH + c;
        const float* up = u_hh + qq * 128;
        float a0 = 0.f, a1 = 0.f, a2 = 0.f, a3 = 0.f;
#pragma unroll 4
        for (int g = 0; g < 128; g += 4) {
            a0 = fmaf(wp[(size_t)(g + 0) * HH], up[g + 0], a0);
            a1 = fmaf(wp[(size_t)(g + 1) * HH], up[g + 1], a1);
            a2 = fmaf(wp[(size_t)(g + 2) * HH], up[g + 2], a2);
            a3 = fmaf(wp[(size_t)(g + 3) * HH], up[g + 3], a3);
        }
        red[tid] = (a0 + a1) + (a2 + a3);
    }

    // ===== Phase A reduction (registers already landed) =====
    {
        float4 S = make_float4(0.f, 0.f, 0.f, 0.f);
        float4 Q = make_float4(0.f, 0.f, 0.f, 0.f);
#pragma unroll
        for (int i = 0; i < 8; ++i) {
            float4 v = xa[i];
            S.x += v.x; S.y += v.y; S.z += v.z; S.w += v.w;
            Q.x = fmaf(v.x, v.x, Q.x); Q.y = fmaf(v.y, v.y, Q.y);
            Q.z = fmaf(v.z, v.z, Q.z); Q.w = fmaf(v.w, v.w, Q.w);
        }
#pragma unroll
        for (int off = 8; off <= 32; off <<= 1) {
            S.x += __shfl_xor(S.x, off, 64); S.y += __shfl_xor(S.y, off, 64);
            S.z += __shfl_xor(S.z, off, 64); S.w += __shfl_xor(S.w, off, 64);
            Q.x += __shfl_xor(Q.x, off, 64); Q.y += __shfl_xor(Q.y, off, 64);
            Q.z += __shfl_xor(Q.z, off, 64); Q.w += __shfl_xor(Q.w, off, 64);
        }
        if (l < 8) { sSS[w][c4] = S; sQQ[w][c4] = Q; }
    }
    __syncthreads();   // publishes red[] (projection) + sSS/sQQ

    // disjoint groups: tid<128 -> vv combine; tid 384..391 -> std combine
    if (tid < 128) vv[tid] = red[tid] + red[tid + 128] + red[tid + 256] + red[tid + 384];
    if (tid >= 384 && tid < 392) {
        const int cc = tid - 384;
        float4 St = make_float4(0.f, 0.f, 0.f, 0.f);
        float4 Qt = make_float4(0.f, 0.f, 0.f, 0.f);
#pragma unroll
        for (int i = 0; i < 8; ++i) {
            float4 a = sSS[i][cc], b4 = sQQ[i][cc];
            St.x += a.x; St.y += a.y; St.z += a.z; St.w += a.w;
            Qt.x += b4.x; Qt.y += b4.y; Qt.z += b4.z; Qt.w += b4.w;
        }
        float st = 0.f;
#pragma unroll
        for (int i = 0; i < 4; ++i) {
            float s1 = (i == 0) ? St.x : (i == 1) ? St.y : (i == 2) ? St.z : St.w;
            float q1 = (i == 0) ? Qt.x : (i == 1) ? Qt.y : (i == 2) ? Qt.z : Qt.w;
            float mean = s1 / 512.0f;
            float var  = (q1 - 512.0f * mean * mean) / 511.0f;
            st += sqrtf(fmaxf(var, 0.f));
        }
        stdp[cc] = st;
    }
    __syncthreads();
    // tid 408: publish ws[b0]; all: square vv for norm reduction
    if (tid == 408) {
        float mm = 0.f;
#pragma unroll
        for (int i = 0; i < 8; ++i) mm += stdp[i];
        __hip_atomic_store(&ws[b0], mm / 32.0f, __ATOMIC_RELAXED,
                           __HIP_MEMORY_SCOPE_AGENT);
    }
    red[tid] = (tid < 128) ? vv[tid] * vv[tid] : 0.f;
    __syncthreads();

    // ===== sigma_hh: norm + W@v =====
    {
        for (int s = 64; s >= 1; s >>= 1) { if (tid < s) red[tid] += red[tid + s]; __syncthreads(); }
        const float nv = sqrtf(red[0]);
        __syncthreads();
        if (tid < 128) vv[tid] = vv[tid] / (nv + EPSF);
        __syncthreads();
        float sq = 0.f;
        float2 vl = *reinterpret_cast<const float2*>(&vv[2 * l]);
#pragma unroll 4
        for (int gi = 0; gi < 64; ++gi) {
            const int g = w * 64 + gi;
            float2 wl = *reinterpret_cast<const float2*>(&w_hh[(size_t)g * HH + 2 * l]);
            float p  = fmaf(wl.x, vl.x, wl.y * vl.y);
            float tot = wave_sum_dpp(p);
            sq = fmaf(tot, tot, sq);
        }
        if (l == 63) red[w] = sq;
        __syncthreads();
        if (tid == 0) {
            float ns2 = 0.f;
            for (int i = 0; i < 8; ++i) ns2 += red[i];
            sigS[1] = ns2 / (sqrtf(ns2) + EPSF);
        }
        __syncthreads();
    }
    // ===== sigma_ih =====
    {
        if (l < CIN) {
            float a0 = 0.f, a1 = 0.f;
#pragma unroll 4
            for (int gi = 0; gi < 64; gi += 2) {
                const int g = w * 64 + gi;
                a0 = fmaf(w_ih[(size_t)(g + 0) * CIN + l], u_ih[g + 0], a0);
                a1 = fmaf(w_ih[(size_t)(g + 1) * CIN + l], u_ih[g + 1], a1);
            }
            red[w * 64 + l] = a0 + a1;
        }
        __syncthreads();
        if (tid < CIN) {
            float v = 0.f;
#pragma unroll
            for (int i = 0; i < 8; ++i) v += red[i * 64 + tid];
            vv[tid] = v;
        }
        __syncthreads();
        if (tid == 0) {
            float n2 = 0.f;
            for (int i = 0; i < CIN; ++i) n2 += vv[i] * vv[i];
            red[400] = sqrtf(n2);
        }
        __syncthreads();
        const float nv = red[400];
        if (tid < CIN) vv[tid] = vv[tid] / (nv + EPSF);
        __syncthreads();
        float vl = (l < CIN) ? vv[l] : 0.f;
        float sq = 0.f;
#pragma unroll 4
        for (int gi = 0; gi < 64; ++gi) {
            const int g = w * 64 + gi;
            float p = (l < CIN) ? w_ih[(size_t)g * CIN + l] * vl : 0.f;
            float tot = wave_sum_dpp(p);
            sq = fmaf(tot, tot, sq);
        }
        if (l == 63) red[w] = sq;
        __syncthreads();
        if (tid == 0) {
            float ns2 = 0.f;
            for (int i = 0; i < 8; ++i) ns2 += red[i];
            sigS[0] = ns2 / (sqrtf(ns2) + EPSF);
        }
        __syncthreads();
    }
    // ===== sigma_fc =====
    {
        red[tid] = (tid < 128) ? fc_w[tid] * fc_w[tid] : 0.f;
        __syncthreads();
        for (int s = 64; s >= 1; s >>= 1) { if (tid < s) red[tid] += red[tid + s]; __syncthreads(); }
        if (tid == 0) {
            float nw2 = red[0];
            float u0  = u_fc[0];
            float nv  = fabsf(u0) * sqrtf(nw2);
            float wv  = u0 * nw2 / (nv + EPSF);
            sigS[2]   = wv * wv / (fabsf(wv) + EPSF);
        }
        __syncthreads();
    }
    const float rih = 1.f / sigS[0];
    const float rhh = 1.f / sigS[1];
    const float rfc = 1.f / sigS[2];
    const float attb = attn_b[0];

    // ================= Phase C: weight conversion =================
    half8 Bf[4][5];
    float biasg[4], w32g[4];
#pragma unroll
    for (int p = 0; p < 4; ++p) {
        const int g = 16 * w + 128 * p + m;
#pragma unroll
        for (int kt = 0; kt < 4; ++kt) {
            const float* src = w_hh + (size_t)g * HH + kt * 32 + q * 8;
#pragma unroll
            for (int i = 0; i < 8; ++i) Bf[p][kt][i] = (_Float16)(src[i] * rhh);
        }
        {
            const float* src = w_ih + (size_t)g * CIN + q * 8;
#pragma unroll
            for (int i = 0; i < 8; ++i) Bf[p][4][i] = (_Float16)(src[i] * rih);
        }
        w32g[p]  = w_ih[(size_t)g * CIN + 32] * rih;
        biasg[p] = b_ih[g] + b_hh[g];
    }
    f32x4 zero4 = (f32x4){0.f, 0.f, 0.f, 0.f};
#pragma unroll
    for (int p = 0; p < 4; ++p) {
#pragma unroll
        for (int kt = 0; kt < 5; ++kt) asm volatile("" : "+v"(Bf[p][kt]));
        asm volatile("" : "+v"(biasg[p]), "+v"(w32g[p]));
    }
    asm volatile("" : "+v"(zero4));
    const float fcwj = fc_w[jcol] * rfc;
    const float aw0 = attn_w[2 * l];
    const float aw1 = attn_w[2 * l + 1];

    // ---- staging: A-row m = timestep t0+m, channels q*8..q*8+7 ----
#define STAGE_LOAD(t0_, xr_)                                                   \
    {                                                                          \
        const size_t base = ((size_t)b0 * TT + (t0_) + m) * CC + q * 8;        \
        xr_[0] = *reinterpret_cast<const float4*>(x + base);                   \
        xr_[1] = *reinterpret_cast<const float4*>(x + base + 4);               \
    }

    // D row 4q+j = timestep t0+4q+j; lane stores gate-interleaved float4.
#define STAGE_COMMIT(t0_, nb_, xr_)                                            \
    {                                                                          \
        half8 af = {(_Float16)xr_[0].x, (_Float16)xr_[0].y,                    \
                    (_Float16)xr_[0].z, (_Float16)xr_[0].w,                    \
                    (_Float16)xr_[1].x, (_Float16)xr_[1].y,                    \
                    (_Float16)xr_[1].z, (_Float16)xr_[1].w};                   \
        f32x4 s0 = MFMA16H(af, Bf[0][4], zero4);                               \
        f32x4 s1 = MFMA16H(af, Bf[1][4], zero4);                               \
        f32x4 s2 = MFMA16H(af, Bf[2][4], zero4);                               \
        f32x4 s3 = MFMA16H(af, Bf[3][4], zero4);                               \
        const int row0 = 4 * q;                                                \
        const float sv0 = load_s(&ws[(t0_) + row0 + 0]);                       \
        const float sv1 = load_s(&ws[(t0_) + row0 + 1]);                       \
        const float sv2 = load_s(&ws[(t0_) + row0 + 2]);                       \
        const float sv3 = load_s(&ws[(t0_) + row0 + 3]);                       \
        _Pragma("unroll")                                                      \
        for (int j = 0; j < 4; ++j) {                                          \
            const float sv = (j == 0) ? sv0 : (j == 1) ? sv1 : (j == 2) ? sv2 : sv3; \
            f32x4 gv;                                                          \
            gv[0] = s0[j] + fmaf(w32g[0], sv, biasg[0]);                       \
            gv[1] = s1[j] + fmaf(w32g[1], sv, biasg[1]);                       \
            gv[2] = s2[j] + fmaf(w32g[2], sv, biasg[2]);                       \
            gv[3] = s3[j] + fmaf(w32g[3], sv, biasg[3]);                       \
            *reinterpret_cast<f32x4*>(&gxs[nb_][row0 + j][jcol * 4]) = gv;     \
        }                                                                      \
    }

    // One LSTM step: 16 MFMA (h-part), 1 b128 gx read, raw barrier.
#define LSTM_STEP(t_, k_, cb_)                                                 \
    {                                                                          \
        const int t  = (t_);                                                   \
        const int hb = (t + 1) & 1;                                            \
        half8 ah0 = *(const half8*)&hs[hb][0 * 32 + q * 8];                    \
        half8 ah1 = *(const half8*)&hs[hb][1 * 32 + q * 8];                    \
        half8 ah2 = *(const half8*)&hs[hb][2 * 32 + q * 8];                    \
        half8 ah3 = *(const half8*)&hs[hb][3 * 32 + q * 8];                    \
        f32x4 gx4 = *reinterpret_cast<const f32x4*>(&gxs[cb_][k_][jcol * 4]);  \
        float dotp = 0.f;                                                      \
        if (t > 0 && w == 7) {                                                 \
            half2v hh = *(const half2v*)&hs[hb][2 * l];                        \
            dotp = fmaf(aw0, (float)hh[0], aw1 * (float)hh[1]);                \
        }                                                                      \
        if (t >= 2) P = fmaf(bcast[(t - 1) & 1], hpp, P);                      \
        f32x4 acc0 = MFMA16H(ah0, Bf[0][0], zero4);                            \
        f32x4 acc1 = MFMA16H(ah0, Bf[1][0], zero4);                            \
        f32x4 acc2 = MFMA16H(ah0, Bf[2][0], zero4);                            \
        f32x4 acc3 = MFMA16H(ah0, Bf[3][0], zero4);                            \
        acc0 = MFMA16H(ah1, Bf[0][1], acc0);                                   \
        acc1 = MFMA16H(ah1, Bf[1][1], acc1);                                   \
        acc2 = MFMA16H(ah1, Bf[2][1], acc2);                                   \
        acc3 = MFMA16H(ah1, Bf[3][1], acc3);                                   \
        acc0 = MFMA16H(ah2, Bf[0][2], acc0);                                   \
        acc1 = MFMA16H(ah2, Bf[1][2], acc1);                                   \
        acc2 = MFMA16H(ah2, Bf[2][2], acc2);                                   \
        acc3 = MFMA16H(ah2, Bf[3][2], acc3);                                   \
        acc0 = MFMA16H(ah3, Bf[0][3], acc0);                                   \
        acc1 = MFMA16H(ah3, Bf[1][3], acc1);                                   \
        acc2 = MFMA16H(ah3, Bf[2][3], acc2);                                   \
        acc3 = MFMA16H(ah3, Bf[3][3], acc3);                                   \
        if (t > 0 && w == 7) {                                                 \
            float tot = wave_sum_dpp(dotp);                                    \
            if (l == 63) {                                                     \
                float beta = __expf(tot + attb);                               \
                Sreg += beta;                                                  \
                bcast[t & 1] = beta;                                           \
            }                                                                  \
        }                                                                      \
        {                                                                      \
            float g0 = acc0[0] + gx4[0];                                       \
            float g1 = acc1[0] + gx4[1];                                       \
            float g2 = acc2[0] + gx4[2];                                       \
            float g3 = acc3[0] + gx4[3];                                       \
            float ig = fsig(g0);                                               \
            float fg = fsig(g1);                                               \
            float gg = ftanh(g2);                                              \
            float og = fsig(g3);                                               \
            c_st = fmaf(fg, c_st, ig * gg);                                    \
            float hv = og * ftanh(c_st);                                       \
            hpp   = hprev;                                                     \
            hprev = hv;                                                        \
            if (q == 0) hs[t & 1][jcol] = (_Float16)hv;                        \
        }                                                                      \
        BARRIER();                                                             \
    }

    // ================= Phase E: lstm main =================
    for (int i = tid; i < 2 * HSP; i += 512) (&hs[0][0])[i] = (_Float16)0.f;

    float c_st = 0.f, P = 0.f, hprev = 0.f, hpp = 0.f;
    float Sreg = 0.f;                                    // lane 63 of wave 7

    {   // chunk-0 gx staging (spins on ws published by all blocks' phase A)
        float4 xr0[2];
        STAGE_LOAD(0, xr0);
        STAGE_COMMIT(0, 0, xr0);
    }
    __syncthreads();

    for (int tc = 0; tc < NCH; ++tc) {
        const int cb  = tc & 1;
        const int t0n = (tc + 1) * CH;
        float4 xr[2];
        if (tc + 1 < NCH) STAGE_LOAD(t0n, xr);           // issue early (T14)
#pragma unroll 2
        for (int k = 0; k < CH / 2; ++k) LSTM_STEP(tc * CH + k, k, cb);
        if (tc + 1 < NCH) STAGE_COMMIT(t0n, cb ^ 1, xr); // commit mid-chunk
#pragma unroll 2
        for (int k = CH / 2; k < CH; ++k) LSTM_STEP(tc * CH + k, k, cb);
    }

    // ---- epilogue ----
    P = fmaf(bcast[1], hpp, P);
    if (w == 7) {
        half2v hh = *(const half2v*)&hs[1][2 * l];
        float dotp = fmaf(aw0, (float)hh[0], aw1 * (float)hh[1]);
        float tot = wave_sum_dpp(dotp);
        if (l == 63) {
            float beta = __expf(tot + attb);
            Sreg += beta;
            bcast[0] = beta;
            SfS = Sreg;
        }
    }
    __syncthreads();
    {
        float Pv = fmaf(bcast[0], hprev, P);
        float v  = Pv * __builtin_amdgcn_rcpf(SfS) * fcwj;
        float rs = row_sum_dpp(v);
        if (l == 15) part[w] = rs;          // q=0 group sums this wave's 16 cols
    }
    __syncthreads();
    if (tid == 0) {
        float a = 0.f;
#pragma unroll
        for (int i = 0; i < 8; ++i) a += part[i];
        out[b0] = a + fc_b[0];
    }
}

// ---------------------------------------------------------------------------
extern "C" void kernel_launch(void* const* d_in, const int* in_sizes, int n_in,
                              void* d_out, int out_size, void* d_ws, size_t ws_size,
                              hipStream_t stream) {
    const float* x      = (const float*)d_in[0];
    const float* w_ih   = (const float*)d_in[1];
    const float* u_ih   = (const float*)d_in[2];
    const float* w_hh   = (const float*)d_in[3];
    const float* u_hh   = (const float*)d_in[4];
    const float* b_ih   = (const float*)d_in[5];
    const float* b_hh   = (const float*)d_in[6];
    const float* attn_w = (const float*)d_in[7];
    const float* attn_b = (const float*)d_in[8];
    const float* fc_w   = (const float*)d_in[9];
    const float* u_fc   = (const float*)d_in[10];
    const float* fc_b   = (const float*)d_in[11];
    float* ws  = (float*)d_ws;
    float* out = (float*)d_out;

    critic_fused<<<BB, 512, 0, stream>>>(x, w_ih, u_ih, w_hh, u_hh, b_ih, b_hh,
                                         attn_w, attn_b, fc_w, u_fc, fc_b, ws, out);
}

// Round 3
// 553.080 us; speedup vs baseline: 1.1404x; 1.1404x over previous
//
#include <hip/hip_runtime.h>
#include <math.h>

#define TT 512
#define BB 512
#define CC 32
#define CIN 33
#define HH 128
#define EPSF 1e-12f
#define CH 16              // timesteps per gx-chunk staged in LDS
#define NCH (TT / CH)
#define RB 2               // batch rows per block
#define HSP 160            // hs row stride (halves): 320 B
#define GXP 520            // gx row stride (floats) per (k,row): 512 data + 8 pad

typedef _Float16 half8 __attribute__((ext_vector_type(8)));
typedef _Float16 half2v __attribute__((ext_vector_type(2)));
typedef float f32x4 __attribute__((ext_vector_type(4)));

#define MFMA16H(a, b, c) __builtin_amdgcn_mfma_f32_16x16x32_f16(a, b, c, 0, 0, 0)
// In-loop barrier: LDS visibility only (no vmcnt drain; staging loads stay in flight).
#define BARRIER() asm volatile("s_waitcnt lgkmcnt(0)\n\ts_barrier" ::: "memory")

__device__ __forceinline__ float fsig(float x) {
    return __builtin_amdgcn_rcpf(1.f + __expf(-x));
}
__device__ __forceinline__ float ftanh(float x) {
    return 1.f - 2.f * __builtin_amdgcn_rcpf(1.f + __expf(2.f * x));
}
// full-wave (64) sum via DPP; result valid on lane 63 ONLY.
__device__ __forceinline__ float wave_sum_dpp(float x) {
    x += __int_as_float(__builtin_amdgcn_update_dpp(0, __float_as_int(x), 0x111, 0xf, 0xf, true));
    x += __int_as_float(__builtin_amdgcn_update_dpp(0, __float_as_int(x), 0x112, 0xf, 0xf, true));
    x += __int_as_float(__builtin_amdgcn_update_dpp(0, __float_as_int(x), 0x114, 0xf, 0xf, true));
    x += __int_as_float(__builtin_amdgcn_update_dpp(0, __float_as_int(x), 0x118, 0xf, 0xf, true));
    x += __int_as_float(__builtin_amdgcn_update_dpp(0, __float_as_int(x), 0x142, 0xa, 0xf, true));
    x += __int_as_float(__builtin_amdgcn_update_dpp(0, __float_as_int(x), 0x143, 0xc, 0xf, true));
    return x;
}
// sum within each 16-lane row; result valid on lanes 15/31/47/63.
__device__ __forceinline__ float row_sum_dpp(float x) {
    x += __int_as_float(__builtin_amdgcn_update_dpp(0, __float_as_int(x), 0x111, 0xf, 0xf, true));
    x += __int_as_float(__builtin_amdgcn_update_dpp(0, __float_as_int(x), 0x112, 0xf, 0xf, true));
    x += __int_as_float(__builtin_amdgcn_update_dpp(0, __float_as_int(x), 0x114, 0xf, 0xf, true));
    x += __int_as_float(__builtin_amdgcn_update_dpp(0, __float_as_int(x), 0x118, 0xf, 0xf, true));
    return x;
}
// spin-load ws[t]: ws is 0xAA-poisoned each launch (sentinel). Relaxed order is
// sufficient; AGENT scope gives cross-XCD visibility. Iteration cap -> worst
// case is a wrong value, never a hang.
__device__ __forceinline__ float load_s(const float* p) {
    float v = __hip_atomic_load(p, __ATOMIC_RELAXED, __HIP_MEMORY_SCOPE_AGENT);
    for (int it = 0; it < 100000000 && __float_as_uint(v) == 0xAAAAAAAAu; ++it)
        v = __hip_atomic_load(p, __ATOMIC_RELAXED, __HIP_MEMORY_SCOPE_AGENT);
    return v;
}

// ---------------------------------------------------------------------------
// R21: row-DE-FUSED double-MFMA step. R19 fused rows 0,1 into one 16-MFMA
// pass; the remaining ~1100cy/step stall (R19: removing MFMAs changed
// nothing; R20: co-residency can't fit registers) is unfillable because all
// waves sit at the same phase. Here each step runs TWO independent 16-MFMA
// passes (row0 broadcast in all A-rows, then row1) -- 2x MFMA issue, but the
// second pass overlaps the sibling wave's DS/extract/act phases, converting
// stall into work. A-frag reads become same-address LDS broadcasts; gx is
// gate-interleaved (1 ds_read_b128); each lane activates only its own row
// (4 cndmask select). Everything outside the step is R19-verified code.
// ---------------------------------------------------------------------------
__global__ __attribute__((amdgpu_flat_work_group_size(512, 512), amdgpu_waves_per_eu(2, 2)))
void critic_fused(
    const float* __restrict__ x,
    const float* __restrict__ w_ih, const float* __restrict__ u_ih,
    const float* __restrict__ w_hh, const float* __restrict__ u_hh,
    const float* __restrict__ b_ih, const float* __restrict__ b_hh,
    const float* __restrict__ attn_w, const float* __restrict__ attn_b,
    const float* __restrict__ fc_w, const float* __restrict__ u_fc,
    const float* __restrict__ fc_b,
    float* __restrict__ ws,
    float* __restrict__ out)
{
    const int tid = threadIdx.x;
    const int w   = tid >> 6;          // wave 0..7
    const int l   = tid & 63;          // lane
    const int m   = l & 15;            // A-row / B-col index
    const int q   = l >> 4;            // quad 0..3
    const int r   = q & 1;             // this lane's batch row (for act/P/epilogue)
    const int b0  = blockIdx.x * RB;
    const int jcol = 16 * w + m;       // this lane's h column

    // ---- LDS (~139 KB -> 1 block/CU) ----
    __shared__ float4 sSS[2][8][8];                         // std wave-partials per tt
    __shared__ float4 sQQ[2][8][8];
    __shared__ float stdp[2][8];                            // per-c4 std partials
    __shared__ float red[512];                              // sigma scratch
    __shared__ float vv[128];
    __shared__ float sigS[3];                               // sig_ih, sig_hh, sig_fc
    __shared__ __align__(16) _Float16 hs[2][RB][HSP];       // h planes
    __shared__ __align__(16) float gxs[2][CH][RB][GXP];     // gate-interleaved gates_x
    __shared__ __align__(8) float bcast[2][RB];             // beta per row
    __shared__ float Sf[RB];
    __shared__ float part[8][RB];                           // FC partials

    // ===== Phase A loads issued FIRST (HBM latency hidden by phase B) =====
    const int c4 = tid & 7;       // c = c4*4 .. c4*4+3
    const int bs = tid >> 3;      // 64 groups of 8 batch rows
    float4 xa[2][8];
#pragma unroll
    for (int tt = 0; tt < 2; ++tt) {
        const int t = 2 * blockIdx.x + tt;
#pragma unroll
        for (int i = 0; i < 8; ++i)
            xa[tt][i] = *reinterpret_cast<const float4*>(
                x + ((size_t)(bs * 8 + i) * TT + t) * CC + c4 * 4);
    }

    // ===== sigma_hh projection in the loads' shadow (L2-bound) =====
    {
        const int c = tid & 127, qq = tid >> 7;
        const float* wp = w_hh + (size_t)(qq * 128) * HH + c;
        const float* up = u_hh + qq * 128;
        float a0 = 0.f, a1 = 0.f, a2 = 0.f, a3 = 0.f;
#pragma unroll 4
        for (int g = 0; g < 128; g += 4) {
            a0 = fmaf(wp[(size_t)(g + 0) * HH], up[g + 0], a0);
            a1 = fmaf(wp[(size_t)(g + 1) * HH], up[g + 1], a1);
            a2 = fmaf(wp[(size_t)(g + 2) * HH], up[g + 2], a2);
            a3 = fmaf(wp[(size_t)(g + 3) * HH], up[g + 3], a3);
        }
        red[tid] = (a0 + a1) + (a2 + a3);
    }

    // ===== Phase A reduction (registers already landed) =====
#pragma unroll
    for (int tt = 0; tt < 2; ++tt) {
        float4 S = make_float4(0.f, 0.f, 0.f, 0.f);
        float4 Q = make_float4(0.f, 0.f, 0.f, 0.f);
#pragma unroll
        for (int i = 0; i < 8; ++i) {
            float4 v = xa[tt][i];
            S.x += v.x; S.y += v.y; S.z += v.z; S.w += v.w;
            Q.x = fmaf(v.x, v.x, Q.x); Q.y = fmaf(v.y, v.y, Q.y);
            Q.z = fmaf(v.z, v.z, Q.z); Q.w = fmaf(v.w, v.w, Q.w);
        }
#pragma unroll
        for (int off = 8; off <= 32; off <<= 1) {
            S.x += __shfl_xor(S.x, off, 64); S.y += __shfl_xor(S.y, off, 64);
            S.z += __shfl_xor(S.z, off, 64); S.w += __shfl_xor(S.w, off, 64);
            Q.x += __shfl_xor(Q.x, off, 64); Q.y += __shfl_xor(Q.y, off, 64);
            Q.z += __shfl_xor(Q.z, off, 64); Q.w += __shfl_xor(Q.w, off, 64);
        }
        if (l < 8) { sSS[tt][w][c4] = S; sQQ[tt][w][c4] = Q; }
    }
    __syncthreads();   // publishes red[] (projection) + sSS/sQQ

    // disjoint groups: tid<128 -> vv combine; tid 384..399 -> std combine
    if (tid < 128) vv[tid] = red[tid] + red[tid + 128] + red[tid + 256] + red[tid + 384];
    if (tid >= 384 && tid < 400) {
        const int tt2 = (tid - 384) >> 3, cc = (tid - 384) & 7;
        float4 St = make_float4(0.f, 0.f, 0.f, 0.f);
        float4 Qt = make_float4(0.f, 0.f, 0.f, 0.f);
#pragma unroll
        for (int i = 0; i < 8; ++i) {
            float4 a = sSS[tt2][i][cc], b4 = sQQ[tt2][i][cc];
            St.x += a.x; St.y += a.y; St.z += a.z; St.w += a.w;
            Qt.x += b4.x; Qt.y += b4.y; Qt.z += b4.z; Qt.w += b4.w;
        }
        float st = 0.f;
#pragma unroll
        for (int i = 0; i < 4; ++i) {
            float s1 = (i == 0) ? St.x : (i == 1) ? St.y : (i == 2) ? St.z : St.w;
            float q1 = (i == 0) ? Qt.x : (i == 1) ? Qt.y : (i == 2) ? Qt.z : Qt.w;
            float mean = s1 / 512.0f;
            float var  = (q1 - 512.0f * mean * mean) / 511.0f;
            st += sqrtf(fmaxf(var, 0.f));
        }
        stdp[tt2][cc] = st;
    }
    __syncthreads();
    // tid 408/409: publish ws[t]; all: square vv for norm reduction
    if (tid >= 408 && tid < 410) {
        const int tt2 = tid - 408;
        float mm = 0.f;
#pragma unroll
        for (int i = 0; i < 8; ++i) mm += stdp[tt2][i];
        __hip_atomic_store(&ws[2 * blockIdx.x + tt2], mm / 32.0f, __ATOMIC_RELAXED,
                           __HIP_MEMORY_SCOPE_AGENT);
    }
    red[tid] = (tid < 128) ? vv[tid] * vv[tid] : 0.f;
    __syncthreads();

    // ===== sigma_hh: norm + W@v =====
    {
        for (int s = 64; s >= 1; s >>= 1) { if (tid < s) red[tid] += red[tid + s]; __syncthreads(); }
        const float nv = sqrtf(red[0]);
        __syncthreads();
        if (tid < 128) vv[tid] = vv[tid] / (nv + EPSF);
        __syncthreads();
        float sq = 0.f;
        float2 vl = *reinterpret_cast<const float2*>(&vv[2 * l]);
#pragma unroll 4
        for (int gi = 0; gi < 64; ++gi) {
            const int g = w * 64 + gi;
            float2 wl = *reinterpret_cast<const float2*>(&w_hh[(size_t)g * HH + 2 * l]);
            float p  = fmaf(wl.x, vl.x, wl.y * vl.y);
            float tot = wave_sum_dpp(p);
            sq = fmaf(tot, tot, sq);
        }
        if (l == 63) red[w] = sq;
        __syncthreads();
        if (tid == 0) {
            float ns2 = 0.f;
            for (int i = 0; i < 8; ++i) ns2 += red[i];
            sigS[1] = ns2 / (sqrtf(ns2) + EPSF);
        }
        __syncthreads();
    }
    // ===== sigma_ih =====
    {
        if (l < CIN) {
            float a0 = 0.f, a1 = 0.f;
#pragma unroll 4
            for (int gi = 0; gi < 64; gi += 2) {
                const int g = w * 64 + gi;
                a0 = fmaf(w_ih[(size_t)(g + 0) * CIN + l], u_ih[g + 0], a0);
                a1 = fmaf(w_ih[(size_t)(g + 1) * CIN + l], u_ih[g + 1], a1);
            }
            red[w * 64 + l] = a0 + a1;
        }
        __syncthreads();
        if (tid < CIN) {
            float v = 0.f;
#pragma unroll
            for (int i = 0; i < 8; ++i) v += red[i * 64 + tid];
            vv[tid] = v;
        }
        __syncthreads();
        if (tid == 0) {
            float n2 = 0.f;
            for (int i = 0; i < CIN; ++i) n2 += vv[i] * vv[i];
            red[400] = sqrtf(n2);
        }
        __syncthreads();
        const float nv = red[400];
        if (tid < CIN) vv[tid] = vv[tid] / (nv + EPSF);
        __syncthreads();
        float vl = (l < CIN) ? vv[l] : 0.f;
        float sq = 0.f;
#pragma unroll 4
        for (int gi = 0; gi < 64; ++gi) {
            const int g = w * 64 + gi;
            float p = (l < CIN) ? w_ih[(size_t)g * CIN + l] * vl : 0.f;
            float tot = wave_sum_dpp(p);
            sq = fmaf(tot, tot, sq);
        }
        if (l == 63) red[w] = sq;
        __syncthreads();
        if (tid == 0) {
            float ns2 = 0.f;
            for (int i = 0; i < 8; ++i) ns2 += red[i];
            sigS[0] = ns2 / (sqrtf(ns2) + EPSF);
        }
        __syncthreads();
    }
    // ===== sigma_fc =====
    {
        red[tid] = (tid < 128) ? fc_w[tid] * fc_w[tid] : 0.f;
        __syncthreads();
        for (int s = 64; s >= 1; s >>= 1) { if (tid < s) red[tid] += red[tid + s]; __syncthreads(); }
        if (tid == 0) {
            float nw2 = red[0];
            float u0  = u_fc[0];
            float nv  = fabsf(u0) * sqrtf(nw2);
            float wv  = u0 * nw2 / (nv + EPSF);
            sigS[2]   = wv * wv / (fabsf(wv) + EPSF);
        }
        __syncthreads();
    }
    const float rih = 1.f / sigS[0];
    const float rhh = 1.f / sigS[1];
    const float rfc = 1.f / sigS[2];
    const float attb = attn_b[0];

    // ================= Phase C: weight conversion =================
    half8 Bf[4][5];
    float biasg[4], w32g[4];
#pragma unroll
    for (int p = 0; p < 4; ++p) {
        const int g = 16 * w + 128 * p + m;
#pragma unroll
        for (int kt = 0; kt < 4; ++kt) {
            const float* src = w_hh + (size_t)g * HH + kt * 32 + q * 8;
#pragma unroll
            for (int i = 0; i < 8; ++i) Bf[p][kt][i] = (_Float16)(src[i] * rhh);
        }
        {
            const float* src = w_ih + (size_t)g * CIN + q * 8;
#pragma unroll
            for (int i = 0; i < 8; ++i) Bf[p][4][i] = (_Float16)(src[i] * rih);
        }
        w32g[p]  = w_ih[(size_t)g * CIN + 32] * rih;
        biasg[p] = b_ih[g] + b_hh[g];
    }
    f32x4 zero4 = (f32x4){0.f, 0.f, 0.f, 0.f};
#pragma unroll
    for (int p = 0; p < 4; ++p) {
#pragma unroll
        for (int kt = 0; kt < 5; ++kt) asm volatile("" : "+v"(Bf[p][kt]));
        asm volatile("" : "+v"(biasg[p]), "+v"(w32g[p]));
    }
    asm volatile("" : "+v"(zero4));
    const float fcwj = fc_w[jcol] * rfc;
    const float aw0 = attn_w[2 * l];
    const float aw1 = attn_w[2 * l + 1];

    // ---- staging: A-row (0..31) = (k,rr) pair; lane m holds row 16*mt+m
    //      -> k = 8*mt+(m>>1), rr = m&1. ----
#define STAGE_LOAD(t0_, xr_)                                                   \
    {                                                                          \
        _Pragma("unroll")                                                      \
        for (int mt = 0; mt < 2; ++mt) {                                       \
            const size_t base =                                                \
                ((size_t)(b0 + (m & 1)) * TT + ((t0_) + 8 * mt + (m >> 1))) *  \
                    CC + q * 8;                                                \
            xr_[mt][0] = *reinterpret_cast<const float4*>(x + base);           \
            xr_[mt][1] = *reinterpret_cast<const float4*>(x + base + 4);       \
        }                                                                      \
    }

    // D row (within mt group) 4q+j -> k = 8mt+2q+(j>>1), rr = j&1.
    // Lane stores gate-interleaved f32x4 (bias + w32*std folded in).
#define STAGE_COMMIT(t0_, nb_, xr_)                                            \
    {                                                                          \
        _Pragma("unroll")                                                      \
        for (int mt = 0; mt < 2; ++mt) {                                       \
            half8 af = {(_Float16)xr_[mt][0].x, (_Float16)xr_[mt][0].y,        \
                        (_Float16)xr_[mt][0].z, (_Float16)xr_[mt][0].w,        \
                        (_Float16)xr_[mt][1].x, (_Float16)xr_[mt][1].y,        \
                        (_Float16)xr_[mt][1].z, (_Float16)xr_[mt][1].w};       \
            f32x4 s0 = MFMA16H(af, Bf[0][4], zero4);                           \
            f32x4 s1 = MFMA16H(af, Bf[1][4], zero4);                           \
            f32x4 s2 = MFMA16H(af, Bf[2][4], zero4);                           \
            f32x4 s3 = MFMA16H(af, Bf[3][4], zero4);                           \
            const float svl = load_s(&ws[(t0_) + 8 * mt + 2 * q]);             \
            const float svh = load_s(&ws[(t0_) + 8 * mt + 2 * q + 1]);         \
            _Pragma("unroll")                                                  \
            for (int j = 0; j < 4; ++j) {                                      \
                const float sv = (j & 2) ? svh : svl;                          \
                f32x4 gv;                                                      \
                gv[0] = s0[j] + fmaf(w32g[0], sv, biasg[0]);                   \
                gv[1] = s1[j] + fmaf(w32g[1], sv, biasg[1]);                   \
                gv[2] = s2[j] + fmaf(w32g[2], sv, biasg[2]);                   \
                gv[3] = s3[j] + fmaf(w32g[3], sv, biasg[3]);                   \
                *reinterpret_cast<f32x4*>(                                     \
                    &gxs[nb_][8 * mt + 2 * q + (j >> 1)][j & 1][jcol * 4]) = gv; \
            }                                                                  \
        }                                                                      \
    }

    // One LSTM step: two de-fused 16-MFMA passes (row0 then row1, broadcast
    // A-frags), gate select by lane row, one act chain, raw barrier.
#define LSTM_STEP(t_, k_, cb_)                                                 \
    {                                                                          \
        const int t  = (t_);                                                   \
        const int hb = (t + 1) & 1;                                            \
        half8 a00 = *(const half8*)&hs[hb][0][0 * 32 + q * 8];                 \
        half8 a01 = *(const half8*)&hs[hb][0][1 * 32 + q * 8];                 \
        half8 a02 = *(const half8*)&hs[hb][0][2 * 32 + q * 8];                 \
        half8 a03 = *(const half8*)&hs[hb][0][3 * 32 + q * 8];                 \
        half8 a10 = *(const half8*)&hs[hb][1][0 * 32 + q * 8];                 \
        half8 a11 = *(const half8*)&hs[hb][1][1 * 32 + q * 8];                 \
        half8 a12 = *(const half8*)&hs[hb][1][2 * 32 + q * 8];                 \
        half8 a13 = *(const half8*)&hs[hb][1][3 * 32 + q * 8];                 \
        f32x4 gx4 = *reinterpret_cast<const f32x4*>(&gxs[cb_][k_][r][jcol * 4]); \
        float dotp = 0.f;                                                      \
        if (t > 0 && w < RB) {                                                 \
            half2v hh = *(const half2v*)&hs[hb][w][2 * l];                     \
            dotp = fmaf(aw0, (float)hh[0], aw1 * (float)hh[1]);                \
        }                                                                      \
        if (t >= 2) P = fmaf(bcast[(t - 1) & 1][r], hpp, P);                   \
        f32x4 acc0 = MFMA16H(a00, Bf[0][0], zero4);                            \
        f32x4 acc1 = MFMA16H(a00, Bf[1][0], zero4);                            \
        f32x4 acc2 = MFMA16H(a00, Bf[2][0], zero4);                            \
        f32x4 acc3 = MFMA16H(a00, Bf[3][0], zero4);                            \
        acc0 = MFMA16H(a01, Bf[0][1], acc0);                                   \
        acc1 = MFMA16H(a01, Bf[1][1], acc1);                                   \
        acc2 = MFMA16H(a01, Bf[2][1], acc2);                                   \
        acc3 = MFMA16H(a01, Bf[3][1], acc3);                                   \
        acc0 = MFMA16H(a02, Bf[0][2], acc0);                                   \
        acc1 = MFMA16H(a02, Bf[1][2], acc1);                                   \
        acc2 = MFMA16H(a02, Bf[2][2], acc2);                                   \
        acc3 = MFMA16H(a02, Bf[3][2], acc3);                                   \
        acc0 = MFMA16H(a03, Bf[0][3], acc0);                                   \
        acc1 = MFMA16H(a03, Bf[1][3], acc1);                                   \
        acc2 = MFMA16H(a03, Bf[2][3], acc2);                                   \
        acc3 = MFMA16H(a03, Bf[3][3], acc3);                                   \
        const float g00 = acc0[0], g01 = acc1[0], g02 = acc2[0], g03 = acc3[0];\
        f32x4 bcc0 = MFMA16H(a10, Bf[0][0], zero4);                            \
        f32x4 bcc1 = MFMA16H(a10, Bf[1][0], zero4);                            \
        f32x4 bcc2 = MFMA16H(a10, Bf[2][0], zero4);                            \
        f32x4 bcc3 = MFMA16H(a10, Bf[3][0], zero4);                            \
        bcc0 = MFMA16H(a11, Bf[0][1], bcc0);                                   \
        bcc1 = MFMA16H(a11, Bf[1][1], bcc1);                                   \
        bcc2 = MFMA16H(a11, Bf[2][1], bcc2);                                   \
        bcc3 = MFMA16H(a11, Bf[3][1], bcc3);                                   \
        bcc0 = MFMA16H(a12, Bf[0][2], bcc0);                                   \
        bcc1 = MFMA16H(a12, Bf[1][2], bcc1);                                   \
        bcc2 = MFMA16H(a12, Bf[2][2], bcc2);                                   \
        bcc3 = MFMA16H(a12, Bf[3][2], bcc3);                                   \
        bcc0 = MFMA16H(a13, Bf[0][3], bcc0);                                   \
        bcc1 = MFMA16H(a13, Bf[1][3], bcc1);                                   \
        bcc2 = MFMA16H(a13, Bf[2][3], bcc2);                                   \
        bcc3 = MFMA16H(a13, Bf[3][3], bcc3);                                   \
        if (t > 0 && w < RB) {                                                 \
            float tot = wave_sum_dpp(dotp);                                    \
            if (l == 63) {                                                     \
                float beta = __expf(tot + attb);                               \
                Sreg += beta;                                                  \
                bcast[t & 1][w] = beta;                                        \
            }                                                                  \
        }                                                                      \
        {                                                                      \
            float g0 = (r ? bcc0[0] : g00) + gx4[0];                           \
            float g1 = (r ? bcc1[0] : g01) + gx4[1];                           \
            float g2 = (r ? bcc2[0] : g02) + gx4[2];                           \
            float g3 = (r ? bcc3[0] : g03) + gx4[3];                           \
            float ig = fsig(g0);                                               \
            float fg = fsig(g1);                                               \
            float gg = ftanh(g2);                                              \
            float og = fsig(g3);                                               \
            c_st = fmaf(fg, c_st, ig * gg);                                    \
            float hv = og * ftanh(c_st);                                       \
            hpp   = hprev;                                                     \
            hprev = hv;                                                        \
            if (q < 2) hs[t & 1][r][jcol] = (_Float16)hv;                      \
        }                                                                      \
        BARRIER();                                                             \
    }

    // ================= Phase E: lstm main =================
    for (int i = tid; i < 2 * RB * HSP; i += 512) (&hs[0][0][0])[i] = (_Float16)0.f;

    float c_st = 0.f, P = 0.f, hprev = 0.f, hpp = 0.f;  // per-lane, row r
    float Sreg = 0.f;                                    // lane 63 of waves 0,1

    {   // chunk-0 gx staging (spins on ws published by all blocks' phase A)
        float4 xr0[2][2];
        STAGE_LOAD(0, xr0);
        STAGE_COMMIT(0, 0, xr0);
    }
    __syncthreads();

    for (int tc = 0; tc < NCH; ++tc) {
        const int cb  = tc & 1;
        const int t0n = (tc + 1) * CH;
        float4 xr[2][2];
        if (tc + 1 < NCH) STAGE_LOAD(t0n, xr);           // issue early (T14)
#pragma unroll 2
        for (int k = 0; k < CH / 2; ++k) LSTM_STEP(tc * CH + k, k, cb);
        if (tc + 1 < NCH) STAGE_COMMIT(t0n, cb ^ 1, xr); // commit mid-chunk
#pragma unroll 2
        for (int k = CH / 2; k < CH; ++k) LSTM_STEP(tc * CH + k, k, cb);
    }

    // ---- epilogue ----
    P = fmaf(bcast[1][r], hpp, P);
    if (w < RB) {
        half2v hh = *(const half2v*)&hs[1][w][2 * l];
        float dotp = fmaf(aw0, (float)hh[0], aw1 * (float)hh[1]);
        float tot = wave_sum_dpp(dotp);
        if (l == 63) {
            float beta = __expf(tot + attb);
            Sreg += beta;
            bcast[0][w] = beta;
            Sf[w] = Sreg;
        }
    }
    __syncthreads();
    {
        float Pv = fmaf(bcast[0][r], hprev, P);
        float v  = Pv * __builtin_amdgcn_rcpf(Sf[r]) * fcwj;
        float rs = row_sum_dpp(v);
        if (l == 15) part[w][0] = rs;       // row 0 sum (q=0)
        if (l == 31) part[w][1] = rs;       // row 1 sum (q=1)
    }
    __syncthreads();
    if (tid < RB) {
        float a = 0.f;
#pragma unroll
        for (int i = 0; i < 8; ++i) a += part[i][tid];
        out[b0 + tid] = a + fc_b[0];
    }
}

// ---------------------------------------------------------------------------
extern "C" void kernel_launch(void* const* d_in, const int* in_sizes, int n_in,
                              void* d_out, int out_size, void* d_ws, size_t ws_size,
                              hipStream_t stream) {
    const float* x      = (const float*)d_in[0];
    const float* w_ih   = (const float*)d_in[1];
    const float* u_ih   = (const float*)d_in[2];
    const float* w_hh   = (const float*)d_in[3];
    const float* u_hh   = (const float*)d_in[4];
    const float* b_ih   = (const float*)d_in[5];
    const float* b_hh   = (const float*)d_in[6];
    const float* attn_w = (const float*)d_in[7];
    const float* attn_b = (const float*)d_in[8];
    const float* fc_w   = (const float*)d_in[9];
    const float* u_fc   = (const float*)d_in[10];
    const float* fc_b   = (const float*)d_in[11];
    float* ws  = (float*)d_ws;
    float* out = (float*)d_out;

    critic_fused<<<BB / RB, 512, 0, stream>>>(x, w_ih, u_ih, w_hh, u_hh, b_ih, b_hh,
                                              attn_w, attn_b, fc_w, u_fc, fc_b, ws, out);
}

// Round 4
// 390.235 us; speedup vs baseline: 1.6163x; 1.4173x over previous
//
#include <hip/hip_runtime.h>
#include <math.h>

#define TT 512
#define BB 512
#define CC 32
#define CIN 33
#define HH 128
#define EPSF 1e-12f
#define CH 16              // timesteps per gx-chunk staged in LDS
#define NCH (TT / CH)
#define RB 2               // batch rows per block
#define HSP 160            // hs row stride (halves): 320 B
#define GXP 520            // gx row stride (floats) per (k,row): 512 data + 8 pad

typedef _Float16 half8 __attribute__((ext_vector_type(8)));
typedef _Float16 half2v __attribute__((ext_vector_type(2)));
typedef float f32x4 __attribute__((ext_vector_type(4)));

#define MFMA16H(a, b, c) __builtin_amdgcn_mfma_f32_16x16x32_f16(a, b, c, 0, 0, 0)
// In-loop barrier: LDS visibility only (no vmcnt drain; staging loads stay in flight).
#define BARRIER() asm volatile("s_waitcnt lgkmcnt(0)\n\ts_barrier" ::: "memory")

__device__ __forceinline__ float fsig(float x) {
    return __builtin_amdgcn_rcpf(1.f + __expf(-x));
}
__device__ __forceinline__ float ftanh(float x) {
    return 1.f - 2.f * __builtin_amdgcn_rcpf(1.f + __expf(2.f * x));
}
// full-wave (64) sum via DPP; result valid on lane 63 ONLY.
__device__ __forceinline__ float wave_sum_dpp(float x) {
    x += __int_as_float(__builtin_amdgcn_update_dpp(0, __float_as_int(x), 0x111, 0xf, 0xf, true));
    x += __int_as_float(__builtin_amdgcn_update_dpp(0, __float_as_int(x), 0x112, 0xf, 0xf, true));
    x += __int_as_float(__builtin_amdgcn_update_dpp(0, __float_as_int(x), 0x114, 0xf, 0xf, true));
    x += __int_as_float(__builtin_amdgcn_update_dpp(0, __float_as_int(x), 0x118, 0xf, 0xf, true));
    x += __int_as_float(__builtin_amdgcn_update_dpp(0, __float_as_int(x), 0x142, 0xa, 0xf, true));
    x += __int_as_float(__builtin_amdgcn_update_dpp(0, __float_as_int(x), 0x143, 0xc, 0xf, true));
    return x;
}
// sum within each 16-lane row; result valid on lanes 15/31/47/63.
__device__ __forceinline__ float row_sum_dpp(float x) {
    x += __int_as_float(__builtin_amdgcn_update_dpp(0, __float_as_int(x), 0x111, 0xf, 0xf, true));
    x += __int_as_float(__builtin_amdgcn_update_dpp(0, __float_as_int(x), 0x112, 0xf, 0xf, true));
    x += __int_as_float(__builtin_amdgcn_update_dpp(0, __float_as_int(x), 0x114, 0xf, 0xf, true));
    x += __int_as_float(__builtin_amdgcn_update_dpp(0, __float_as_int(x), 0x118, 0xf, 0xf, true));
    return x;
}
// spin-load ws[t]: ws is 0xAA-poisoned each launch (sentinel). Relaxed order is
// sufficient; AGENT scope gives cross-XCD visibility. Iteration cap -> worst
// case is a wrong value, never a hang.
__device__ __forceinline__ float load_s(const float* p) {
    float v = __hip_atomic_load(p, __ATOMIC_RELAXED, __HIP_MEMORY_SCOPE_AGENT);
    for (int it = 0; it < 100000000 && __float_as_uint(v) == 0xAAAAAAAAu; ++it)
        v = __hip_atomic_load(p, __ATOMIC_RELAXED, __HIP_MEMORY_SCOPE_AGENT);
    return v;
}

// ---------------------------------------------------------------------------
// R22: wave specialization. Waves 0-3 = compute (32 gate-cols each, 32 MFMA/
// step, 8 indep acc chains; per-SIMD MFMA count unchanged vs R19). Waves 4-7 =
// service: chunk staging (x load k=0, ws spin k=4, gx commit k=8) + attn
// logits (waves 4,5). This removes the logit straggler tail, the commit burst
// and the global spin from the compute critical path, and cuts the per-step
// DS burst ~40%. BREG register file shared between roles (staging aliases Wih
// frags into BREG[p][sub][0]) to stay <=256 VGPR at 2 waves/SIMD.
// ---------------------------------------------------------------------------
__global__ __attribute__((amdgpu_flat_work_group_size(512, 512), amdgpu_waves_per_eu(2, 2)))
void critic_fused(
    const float* __restrict__ x,
    const float* __restrict__ w_ih, const float* __restrict__ u_ih,
    const float* __restrict__ w_hh, const float* __restrict__ u_hh,
    const float* __restrict__ b_ih, const float* __restrict__ b_hh,
    const float* __restrict__ attn_w, const float* __restrict__ attn_b,
    const float* __restrict__ fc_w, const float* __restrict__ u_fc,
    const float* __restrict__ fc_b,
    float* __restrict__ ws,
    float* __restrict__ out)
{
    const int tid = threadIdx.x;
    const int w   = tid >> 6;          // wave 0..7
    const int l   = tid & 63;          // lane
    const int m   = l & 15;            // A-row / B-col index
    const int q   = l >> 4;            // quad 0..3
    const int b0  = blockIdx.x * RB;
    const int sw  = w - 4;             // service wave id (valid for w>=4)
    const int col = 32 * (w & 3) + (l & 31);  // compute lane's h column
    const int row = l >> 5;            // compute lane's batch row
    const int sub = (l >> 4) & 1;      // compute lane's col-subtile

    // ---- LDS (~141 KB -> 1 block/CU) ----
    __shared__ float4 sSS[2][8][8];                         // std wave-partials per tt
    __shared__ float4 sQQ[2][8][8];
    __shared__ float stdp[2][8];                            // per-c4 std partials
    __shared__ float red[512];                              // sigma scratch
    __shared__ float vv[128];
    __shared__ float sigS[3];                               // sig_ih, sig_hh, sig_fc
    __shared__ __align__(16) _Float16 hs[2][RB][HSP];       // h planes
    __shared__ __align__(16) float gxs[2][CH][RB][GXP];     // gate-interleaved gates_x
    __shared__ __align__(8) float bcast[2][RB];             // beta per row
    __shared__ float Sf[RB];
    __shared__ float part[4][4];                            // FC partials

    // ===== Phase A loads issued FIRST (HBM latency hidden by phase B) =====
    const int c4 = tid & 7;       // c = c4*4 .. c4*4+3
    const int bs = tid >> 3;      // 64 groups of 8 batch rows
    float4 xa[2][8];
#pragma unroll
    for (int tt = 0; tt < 2; ++tt) {
        const int t = 2 * blockIdx.x + tt;
#pragma unroll
        for (int i = 0; i < 8; ++i)
            xa[tt][i] = *reinterpret_cast<const float4*>(
                x + ((size_t)(bs * 8 + i) * TT + t) * CC + c4 * 4);
    }

    // ===== sigma_hh projection in the loads' shadow (L2-bound) =====
    {
        const int c = tid & 127, qq = tid >> 7;
        const float* wp = w_hh + (size_t)(qq * 128) * HH + c;
        const float* up = u_hh + qq * 128;
        float a0 = 0.f, a1 = 0.f, a2 = 0.f, a3 = 0.f;
#pragma unroll 4
        for (int g = 0; g < 128; g += 4) {
            a0 = fmaf(wp[(size_t)(g + 0) * HH], up[g + 0], a0);
            a1 = fmaf(wp[(size_t)(g + 1) * HH], up[g + 1], a1);
            a2 = fmaf(wp[(size_t)(g + 2) * HH], up[g + 2], a2);
            a3 = fmaf(wp[(size_t)(g + 3) * HH], up[g + 3], a3);
        }
        red[tid] = (a0 + a1) + (a2 + a3);
    }

    // ===== Phase A reduction (registers already landed) =====
#pragma unroll
    for (int tt = 0; tt < 2; ++tt) {
        float4 S = make_float4(0.f, 0.f, 0.f, 0.f);
        float4 Q = make_float4(0.f, 0.f, 0.f, 0.f);
#pragma unroll
        for (int i = 0; i < 8; ++i) {
            float4 v = xa[tt][i];
            S.x += v.x; S.y += v.y; S.z += v.z; S.w += v.w;
            Q.x = fmaf(v.x, v.x, Q.x); Q.y = fmaf(v.y, v.y, Q.y);
            Q.z = fmaf(v.z, v.z, Q.z); Q.w = fmaf(v.w, v.w, Q.w);
        }
#pragma unroll
        for (int off = 8; off <= 32; off <<= 1) {
            S.x += __shfl_xor(S.x, off, 64); S.y += __shfl_xor(S.y, off, 64);
            S.z += __shfl_xor(S.z, off, 64); S.w += __shfl_xor(S.w, off, 64);
            Q.x += __shfl_xor(Q.x, off, 64); Q.y += __shfl_xor(Q.y, off, 64);
            Q.z += __shfl_xor(Q.z, off, 64); Q.w += __shfl_xor(Q.w, off, 64);
        }
        if (l < 8) { sSS[tt][w][c4] = S; sQQ[tt][w][c4] = Q; }
    }
    __syncthreads();   // publishes red[] (projection) + sSS/sQQ

    // disjoint groups: tid<128 -> vv combine; tid 384..399 -> std combine
    if (tid < 128) vv[tid] = red[tid] + red[tid + 128] + red[tid + 256] + red[tid + 384];
    if (tid >= 384 && tid < 400) {
        const int tt2 = (tid - 384) >> 3, cc = (tid - 384) & 7;
        float4 St = make_float4(0.f, 0.f, 0.f, 0.f);
        float4 Qt = make_float4(0.f, 0.f, 0.f, 0.f);
#pragma unroll
        for (int i = 0; i < 8; ++i) {
            float4 a = sSS[tt2][i][cc], b4 = sQQ[tt2][i][cc];
            St.x += a.x; St.y += a.y; St.z += a.z; St.w += a.w;
            Qt.x += b4.x; Qt.y += b4.y; Qt.z += b4.z; Qt.w += b4.w;
        }
        float st = 0.f;
#pragma unroll
        for (int i = 0; i < 4; ++i) {
            float s1 = (i == 0) ? St.x : (i == 1) ? St.y : (i == 2) ? St.z : St.w;
            float q1 = (i == 0) ? Qt.x : (i == 1) ? Qt.y : (i == 2) ? Qt.z : Qt.w;
            float mean = s1 / 512.0f;
            float var  = (q1 - 512.0f * mean * mean) / 511.0f;
            st += sqrtf(fmaxf(var, 0.f));
        }
        stdp[tt2][cc] = st;
    }
    __syncthreads();
    // tid 408/409: publish ws[t]; all: square vv for norm reduction
    if (tid >= 408 && tid < 410) {
        const int tt2 = tid - 408;
        float mm = 0.f;
#pragma unroll
        for (int i = 0; i < 8; ++i) mm += stdp[tt2][i];
        __hip_atomic_store(&ws[2 * blockIdx.x + tt2], mm / 32.0f, __ATOMIC_RELAXED,
                           __HIP_MEMORY_SCOPE_AGENT);
    }
    red[tid] = (tid < 128) ? vv[tid] * vv[tid] : 0.f;
    __syncthreads();

    // ===== sigma_hh: norm + W@v =====
    {
        for (int s = 64; s >= 1; s >>= 1) { if (tid < s) red[tid] += red[tid + s]; __syncthreads(); }
        const float nv = sqrtf(red[0]);
        __syncthreads();
        if (tid < 128) vv[tid] = vv[tid] / (nv + EPSF);
        __syncthreads();
        float sq = 0.f;
        float2 vl = *reinterpret_cast<const float2*>(&vv[2 * l]);
#pragma unroll 4
        for (int gi = 0; gi < 64; ++gi) {
            const int g = w * 64 + gi;
            float2 wl = *reinterpret_cast<const float2*>(&w_hh[(size_t)g * HH + 2 * l]);
            float p  = fmaf(wl.x, vl.x, wl.y * vl.y);
            float tot = wave_sum_dpp(p);
            sq = fmaf(tot, tot, sq);
        }
        if (l == 63) red[w] = sq;
        __syncthreads();
        if (tid == 0) {
            float ns2 = 0.f;
            for (int i = 0; i < 8; ++i) ns2 += red[i];
            sigS[1] = ns2 / (sqrtf(ns2) + EPSF);
        }
        __syncthreads();
    }
    // ===== sigma_ih =====
    {
        if (l < CIN) {
            float a0 = 0.f, a1 = 0.f;
#pragma unroll 4
            for (int gi = 0; gi < 64; gi += 2) {
                const int g = w * 64 + gi;
                a0 = fmaf(w_ih[(size_t)(g + 0) * CIN + l], u_ih[g + 0], a0);
                a1 = fmaf(w_ih[(size_t)(g + 1) * CIN + l], u_ih[g + 1], a1);
            }
            red[w * 64 + l] = a0 + a1;
        }
        __syncthreads();
        if (tid < CIN) {
            float v = 0.f;
#pragma unroll
            for (int i = 0; i < 8; ++i) v += red[i * 64 + tid];
            vv[tid] = v;
        }
        __syncthreads();
        if (tid == 0) {
            float n2 = 0.f;
            for (int i = 0; i < CIN; ++i) n2 += vv[i] * vv[i];
            red[400] = sqrtf(n2);
        }
        __syncthreads();
        const float nv = red[400];
        if (tid < CIN) vv[tid] = vv[tid] / (nv + EPSF);
        __syncthreads();
        float vl = (l < CIN) ? vv[l] : 0.f;
        float sq = 0.f;
#pragma unroll 4
        for (int gi = 0; gi < 64; ++gi) {
            const int g = w * 64 + gi;
            float p = (l < CIN) ? w_ih[(size_t)g * CIN + l] * vl : 0.f;
            float tot = wave_sum_dpp(p);
            sq = fmaf(tot, tot, sq);
        }
        if (l == 63) red[w] = sq;
        __syncthreads();
        if (tid == 0) {
            float ns2 = 0.f;
            for (int i = 0; i < 8; ++i) ns2 += red[i];
            sigS[0] = ns2 / (sqrtf(ns2) + EPSF);
        }
        __syncthreads();
    }
    // ===== sigma_fc =====
    {
        red[tid] = (tid < 128) ? fc_w[tid] * fc_w[tid] : 0.f;
        __syncthreads();
        for (int s = 64; s >= 1; s >>= 1) { if (tid < s) red[tid] += red[tid + s]; __syncthreads(); }
        if (tid == 0) {
            float nw2 = red[0];
            float u0  = u_fc[0];
            float nv  = fabsf(u0) * sqrtf(nw2);
            float wv  = u0 * nw2 / (nv + EPSF);
            sigS[2]   = wv * wv / (fabsf(wv) + EPSF);
        }
        __syncthreads();
    }
    const float rih = 1.f / sigS[0];
    const float rhh = 1.f / sigS[1];
    const float rfc = 1.f / sigS[2];
    const float attb = attn_b[0];

    // ================= Phase C: role-split weight conversion =================
    // compute (w<4): BREG[p][sub][kt] = Whh B-frags for cols 32w+16sub+m.
    // service (w>=4): BREG[p][sub][0] aliased as Wih B-frags for its cols.
    half8 BREG[4][2][4];
    float biasg[4][2], w32g[4][2];
    float fcwj = 0.f, aw0 = 0.f, aw1 = 0.f;
    f32x4 zero4 = (f32x4){0.f, 0.f, 0.f, 0.f};
    if (w < 4) {
#pragma unroll
        for (int p = 0; p < 4; ++p)
#pragma unroll
            for (int s = 0; s < 2; ++s) {
                const int g = 128 * p + 32 * w + 16 * s + m;
#pragma unroll
                for (int kt = 0; kt < 4; ++kt) {
                    const float* src = w_hh + (size_t)g * HH + kt * 32 + q * 8;
#pragma unroll
                    for (int i = 0; i < 8; ++i) BREG[p][s][kt][i] = (_Float16)(src[i] * rhh);
                }
            }
#pragma unroll
        for (int p = 0; p < 4; ++p)
#pragma unroll
            for (int s = 0; s < 2; ++s)
#pragma unroll
                for (int kt = 0; kt < 4; ++kt) asm volatile("" : "+v"(BREG[p][s][kt]));
        fcwj = fc_w[col] * rfc;
    } else {
#pragma unroll
        for (int p = 0; p < 4; ++p)
#pragma unroll
            for (int s = 0; s < 2; ++s) {
                const int g = 128 * p + 32 * sw + 16 * s + m;
                const float* src = w_ih + (size_t)g * CIN + q * 8;
#pragma unroll
                for (int i = 0; i < 8; ++i) BREG[p][s][0][i] = (_Float16)(src[i] * rih);
                w32g[p][s]  = w_ih[(size_t)g * CIN + 32] * rih;
                biasg[p][s] = b_ih[g] + b_hh[g];
                asm volatile("" : "+v"(BREG[p][s][0]));
                asm volatile("" : "+v"(biasg[p][s]), "+v"(w32g[p][s]));
            }
        aw0 = attn_w[2 * l];
        aw1 = attn_w[2 * l + 1];
    }
    asm volatile("" : "+v"(zero4));

    // ---- staging: A-row (0..31) = (k,rr) pair; lane m holds rows m, m+16
    //      -> k = 8*mt+(m>>1), rr = m&1. ----
#define STAGE_LOAD(t0_, xr_)                                                   \
    {                                                                          \
        _Pragma("unroll")                                                      \
        for (int mt = 0; mt < 2; ++mt) {                                       \
            const size_t base =                                                \
                ((size_t)(b0 + (m & 1)) * TT + ((t0_) + 8 * mt + (m >> 1))) *  \
                    CC + q * 8;                                                \
            xr_[mt][0] = *reinterpret_cast<const float4*>(x + base);           \
            xr_[mt][1] = *reinterpret_cast<const float4*>(x + base + 4);       \
        }                                                                      \
    }

#define STAGE_SPIN(t0_, svr_)                                                  \
    {                                                                          \
        svr_[0] = load_s(&ws[(t0_) + 2 * q]);                                  \
        svr_[1] = load_s(&ws[(t0_) + 2 * q + 1]);                              \
        svr_[2] = load_s(&ws[(t0_) + 8 + 2 * q]);                              \
        svr_[3] = load_s(&ws[(t0_) + 8 + 2 * q + 1]);                          \
    }

    // D row (within mt) 4q+j -> k = 8mt+2q+(j>>1), rr = j&1. Lane writes
    // gate-interleaved f32x4 (bias + w32*std folded) for its service cols.
#define STAGE_COMMIT(nb_, xr_, svr_)                                           \
    {                                                                          \
        _Pragma("unroll")                                                      \
        for (int mt = 0; mt < 2; ++mt) {                                       \
            half8 af = {(_Float16)xr_[mt][0].x, (_Float16)xr_[mt][0].y,        \
                        (_Float16)xr_[mt][0].z, (_Float16)xr_[mt][0].w,        \
                        (_Float16)xr_[mt][1].x, (_Float16)xr_[mt][1].y,        \
                        (_Float16)xr_[mt][1].z, (_Float16)xr_[mt][1].w};       \
            _Pragma("unroll")                                                  \
            for (int s = 0; s < 2; ++s) {                                      \
                f32x4 s0 = MFMA16H(af, BREG[0][s][0], zero4);                  \
                f32x4 s1 = MFMA16H(af, BREG[1][s][0], zero4);                  \
                f32x4 s2 = MFMA16H(af, BREG[2][s][0], zero4);                  \
                f32x4 s3 = MFMA16H(af, BREG[3][s][0], zero4);                  \
                _Pragma("unroll")                                              \
                for (int j = 0; j < 4; ++j) {                                  \
                    const float sv = (j & 2) ? svr_[2 * mt + 1] : svr_[2 * mt];\
                    f32x4 gv;                                                  \
                    gv[0] = s0[j] + fmaf(w32g[0][s], sv, biasg[0][s]);         \
                    gv[1] = s1[j] + fmaf(w32g[1][s], sv, biasg[1][s]);         \
                    gv[2] = s2[j] + fmaf(w32g[2][s], sv, biasg[2][s]);         \
                    gv[3] = s3[j] + fmaf(w32g[3][s], sv, biasg[3][s]);         \
                    *reinterpret_cast<f32x4*>(                                 \
                        &gxs[nb_][8 * mt + 2 * q + (j >> 1)][j & 1]            \
                            [(32 * sw + 16 * s + m) * 4]) = gv;                \
                }                                                              \
            }                                                                  \
        }                                                                      \
    }

    // ================= Phase E: lstm main =================
    for (int i = tid; i < 2 * RB * HSP; i += 512) (&hs[0][0][0])[i] = (_Float16)0.f;

    float c_st = 0.f, P = 0.f, hprev = 0.f, hpp = 0.f;  // compute lanes
    float Sreg = 0.f;                                    // service 4,5 lane 63
    float4 xr[2][2];
    float svr[4];

    if (w >= 4) {   // chunk-0 staging (spins on ws published by all blocks)
        STAGE_LOAD(0, xr);
        STAGE_SPIN(0, svr);
        STAGE_COMMIT(0, xr, svr);
    }
    __syncthreads();

    for (int tc = 0; tc < NCH; ++tc) {
        const int cb  = tc & 1;
        const int t0n = (tc + 1) * CH;
#pragma unroll 2
        for (int k = 0; k < CH; ++k) {
            const int t  = tc * CH + k;
            const int hb = (t + 1) & 1;
            if (w < 4) {
                // ---------------- compute step ----------------
                half8 ah0 = *(const half8*)&hs[hb][m & 1][0 * 32 + q * 8];
                half8 ah1 = *(const half8*)&hs[hb][m & 1][1 * 32 + q * 8];
                half8 ah2 = *(const half8*)&hs[hb][m & 1][2 * 32 + q * 8];
                half8 ah3 = *(const half8*)&hs[hb][m & 1][3 * 32 + q * 8];
                f32x4 gx4 = *reinterpret_cast<const f32x4*>(&gxs[cb][k][row][col * 4]);
                if (t >= 2) P = fmaf(bcast[(t - 1) & 1][row], hpp, P);
                f32x4 c00 = MFMA16H(ah0, BREG[0][0][0], zero4);
                f32x4 c10 = MFMA16H(ah0, BREG[0][1][0], zero4);
                f32x4 c01 = MFMA16H(ah0, BREG[1][0][0], zero4);
                f32x4 c11 = MFMA16H(ah0, BREG[1][1][0], zero4);
                f32x4 c02 = MFMA16H(ah0, BREG[2][0][0], zero4);
                f32x4 c12 = MFMA16H(ah0, BREG[2][1][0], zero4);
                f32x4 c03 = MFMA16H(ah0, BREG[3][0][0], zero4);
                f32x4 c13 = MFMA16H(ah0, BREG[3][1][0], zero4);
                c00 = MFMA16H(ah1, BREG[0][0][1], c00);
                c10 = MFMA16H(ah1, BREG[0][1][1], c10);
                c01 = MFMA16H(ah1, BREG[1][0][1], c01);
                c11 = MFMA16H(ah1, BREG[1][1][1], c11);
                c02 = MFMA16H(ah1, BREG[2][0][1], c02);
                c12 = MFMA16H(ah1, BREG[2][1][1], c12);
                c03 = MFMA16H(ah1, BREG[3][0][1], c03);
                c13 = MFMA16H(ah1, BREG[3][1][1], c13);
                c00 = MFMA16H(ah2, BREG[0][0][2], c00);
                c10 = MFMA16H(ah2, BREG[0][1][2], c10);
                c01 = MFMA16H(ah2, BREG[1][0][2], c01);
                c11 = MFMA16H(ah2, BREG[1][1][2], c11);
                c02 = MFMA16H(ah2, BREG[2][0][2], c02);
                c12 = MFMA16H(ah2, BREG[2][1][2], c12);
                c03 = MFMA16H(ah2, BREG[3][0][2], c03);
                c13 = MFMA16H(ah2, BREG[3][1][2], c13);
                c00 = MFMA16H(ah3, BREG[0][0][3], c00);
                c10 = MFMA16H(ah3, BREG[0][1][3], c10);
                c01 = MFMA16H(ah3, BREG[1][0][3], c01);
                c11 = MFMA16H(ah3, BREG[1][1][3], c11);
                c02 = MFMA16H(ah3, BREG[2][0][3], c02);
                c12 = MFMA16H(ah3, BREG[2][1][3], c12);
                c03 = MFMA16H(ah3, BREG[3][0][3], c03);
                c13 = MFMA16H(ah3, BREG[3][1][3], c13);
                // D reg j holds batch row j&1; select reg by row, acc by sub.
                float g0 = (sub ? (row ? c10[1] : c10[0]) : (row ? c00[1] : c00[0])) + gx4[0];
                float g1 = (sub ? (row ? c11[1] : c11[0]) : (row ? c01[1] : c01[0])) + gx4[1];
                float g2 = (sub ? (row ? c12[1] : c12[0]) : (row ? c02[1] : c02[0])) + gx4[2];
                float g3 = (sub ? (row ? c13[1] : c13[0]) : (row ? c03[1] : c03[0])) + gx4[3];
                float ig = fsig(g0);
                float fg = fsig(g1);
                float gg = ftanh(g2);
                float og = fsig(g3);
                c_st = fmaf(fg, c_st, ig * gg);
                float hv = og * ftanh(c_st);
                hpp   = hprev;
                hprev = hv;
                hs[t & 1][row][col] = (_Float16)hv;
            } else {
                // ---------------- service step ----------------
                if (sw < 2 && t > 0) {
                    half2v hh = *(const half2v*)&hs[hb][sw][2 * l];
                    float dotp = fmaf(aw0, (float)hh[0], aw1 * (float)hh[1]);
                    float tot = wave_sum_dpp(dotp);
                    if (l == 63) {
                        float beta = __expf(tot + attb);
                        Sreg += beta;
                        bcast[t & 1][sw] = beta;
                    }
                }
                if (tc + 1 < NCH) {
                    if (k == 0) STAGE_LOAD(t0n, xr);
                    if (k == 4) STAGE_SPIN(t0n, svr);
                    if (k == 8) STAGE_COMMIT(cb ^ 1, xr, svr);
                }
            }
            BARRIER();
        }
    }

    // ---- epilogue ----
    if (w < 4) P = fmaf(bcast[1][row], hpp, P);
    if (w >= 4 && sw < 2) {
        half2v hh = *(const half2v*)&hs[1][sw][2 * l];
        float dotp = fmaf(aw0, (float)hh[0], aw1 * (float)hh[1]);
        float tot = wave_sum_dpp(dotp);
        if (l == 63) {
            float beta = __expf(tot + attb);
            Sreg += beta;
            bcast[0][sw] = beta;
            Sf[sw] = Sreg;
        }
    }
    __syncthreads();
    if (w < 4) {
        float Pv = fmaf(bcast[0][row], hprev, P);
        float v  = Pv * __builtin_amdgcn_rcpf(Sf[row]) * fcwj;
        float rs = row_sum_dpp(v);
        if ((l & 15) == 15) part[w][q] = rs;   // q: 0,1 -> row0 subtiles; 2,3 -> row1
    }
    __syncthreads();
    if (tid < RB) {
        float a = 0.f;
#pragma unroll
        for (int i = 0; i < 4; ++i) a += part[i][2 * tid] + part[i][2 * tid + 1];
        out[b0 + tid] = a + fc_b[0];
    }
}

// ---------------------------------------------------------------------------
extern "C" void kernel_launch(void* const* d_in, const int* in_sizes, int n_in,
                              void* d_out, int out_size, void* d_ws, size_t ws_size,
                              hipStream_t stream) {
    const float* x      = (const float*)d_in[0];
    const float* w_ih   = (const float*)d_in[1];
    const float* u_ih   = (const float*)d_in[2];
    const float* w_hh   = (const float*)d_in[3];
    const float* u_hh   = (const float*)d_in[4];
    const float* b_ih   = (const float*)d_in[5];
    const float* b_hh   = (const float*)d_in[6];
    const float* attn_w = (const float*)d_in[7];
    const float* attn_b = (const float*)d_in[8];
    const float* fc_w   = (const float*)d_in[9];
    const float* u_fc   = (const float*)d_in[10];
    const float* fc_b   = (const float*)d_in[11];
    float* ws  = (float*)d_ws;
    float* out = (float*)d_out;

    critic_fused<<<BB / RB, 512, 0, stream>>>(x, w_ih, u_ih, w_hh, u_hh, b_ih, b_hh,
                                              attn_w, attn_b, fc_w, u_fc, fc_b, ws, out);
}